// Round 9
// baseline (393.836 us; speedup 1.0000x reference)
//
#include <hip/hip_runtime.h>
#include <math.h>

#define NB    64        // graphs
#define NPER  1024      // nodes per graph
#define NTOT  65536     // total nodes
#define ETOT  1048576   // edges
#define FEAT  64
#define HID   128
#define KSEL  10
#define MAXDEG 64       // CSR slot capacity per node (max in-degree ~40)

// Pipeline (agg commuted before the weight multiply, dinv folded into gemm output):
//   AT = agg(Z)            agg_k  : LDS-staged gather, THREAD-PER-NODE; out feature-major
//   Z' = relu(AT@W+b)*dinv gemm_k : 64x128 tile; A-stage = straight b128 copy
// Layouts: Z chunk-major C[c][v][16]; AT feature-major [k][v]; col16 slot-major u16.

// ---------------- init: zero cnt + part (replaces two memsets) ----------------------
__global__ __launch_bounds__(256) void init_k(int* __restrict__ cnt,
                                              float* __restrict__ part) {
    int v = blockIdx.x * 256 + threadIdx.x;
    cnt[v] = 0;
    if (v < NB * 128) part[v] = 0.f;
}

// ---------------- CSR build (slot-major, u16 local index) ----------------
__global__ __launch_bounds__(256) void csr_k(const int* __restrict__ src,
                                             const int* __restrict__ dst,
                                             int* __restrict__ cnt,
                                             unsigned short* __restrict__ col16) {
    int e = blockIdx.x * 256 + threadIdx.x;
    if (e >= ETOT) return;
    int d = dst[e];
    int s = src[e];
    int pos = atomicAdd(&cnt[d], 1);
    col16[(size_t)pos * NTOT + d] = (unsigned short)(s & (NPER - 1));
}

// ---------------- LDS-staged aggregation, thread-per-node --------------------------
// block=(graph g, chunk c); 1024 threads = 1024 nodes; each thread owns the full
// 16-feature chunk of its node (4 float4 accumulators). Z input pre-scaled by dinv;
// x input (conv0) scaled at staging. out_v = dv * sum(staged over {v} u N(v)).
__global__ __launch_bounds__(1024) void agg_k(const float* __restrict__ Z,
                                              const float* __restrict__ x,
                                              const unsigned short* __restrict__ col16,
                                              const int* __restrict__ cnt,
                                              float* __restrict__ outAT,
                                              int cshift,
                                              float* __restrict__ fvec) {
    __shared__ float4 sy4[4096];   // 64 KB
    int t = threadIdx.x;
    int g = blockIdx.x >> cshift;
    int c = blockIdx.x & ((1 << cshift) - 1);
    int gbase = g << 10;

    if (x) {
#pragma unroll
        for (int j = 0; j < 4; ++j) {
            int fl = j * 1024 + t;
            int v = fl >> 2, q = fl & 3;
            float dvv = rsqrtf((float)cnt[gbase + v] + 1.0f);
            float4 z = *(const float4*)&x[(size_t)(gbase + v) * FEAT + c * 16 + q * 4];
            z.x *= dvv; z.y *= dvv; z.z *= dvv; z.w *= dvv;
            sy4[fl] = z;
        }
    } else {
        const float4* Zg4 = (const float4*)(Z + ((size_t)c * NTOT + gbase) * 16);
#pragma unroll
        for (int j = 0; j < 4; ++j) sy4[j * 1024 + t] = Zg4[j * 1024 + t];
    }
    __syncthreads();

    int gv = gbase + t;
    int n = cnt[gv];
    float dv = rsqrtf((float)n + 1.0f);
    const unsigned short* ip = col16 + gv;

    float4 acc0 = sy4[t * 4 + 0];   // self term
    float4 acc1 = sy4[t * 4 + 1];
    float4 acc2 = sy4[t * 4 + 2];
    float4 acc3 = sy4[t * 4 + 3];

    int i = 0;
    for (; i + 2 <= n; i += 2) {
        int na = ip[(size_t)i * NTOT];
        int nb = ip[(size_t)(i + 1) * NTOT];
        float4 ya, yb;
        ya = sy4[na * 4 + 0]; yb = sy4[nb * 4 + 0];
        acc0.x += ya.x + yb.x; acc0.y += ya.y + yb.y;
        acc0.z += ya.z + yb.z; acc0.w += ya.w + yb.w;
        ya = sy4[na * 4 + 1]; yb = sy4[nb * 4 + 1];
        acc1.x += ya.x + yb.x; acc1.y += ya.y + yb.y;
        acc1.z += ya.z + yb.z; acc1.w += ya.w + yb.w;
        ya = sy4[na * 4 + 2]; yb = sy4[nb * 4 + 2];
        acc2.x += ya.x + yb.x; acc2.y += ya.y + yb.y;
        acc2.z += ya.z + yb.z; acc2.w += ya.w + yb.w;
        ya = sy4[na * 4 + 3]; yb = sy4[nb * 4 + 3];
        acc3.x += ya.x + yb.x; acc3.y += ya.y + yb.y;
        acc3.z += ya.z + yb.z; acc3.w += ya.w + yb.w;
    }
    if (i < n) {
        int na = ip[(size_t)i * NTOT];
        float4 ya;
        ya = sy4[na * 4 + 0];
        acc0.x += ya.x; acc0.y += ya.y; acc0.z += ya.z; acc0.w += ya.w;
        ya = sy4[na * 4 + 1];
        acc1.x += ya.x; acc1.y += ya.y; acc1.z += ya.z; acc1.w += ya.w;
        ya = sy4[na * 4 + 2];
        acc2.x += ya.x; acc2.y += ya.y; acc2.z += ya.z; acc2.w += ya.w;
        ya = sy4[na * 4 + 3];
        acc3.x += ya.x; acc3.y += ya.y; acc3.z += ya.z; acc3.w += ya.w;
    }

    acc0.x *= dv; acc0.y *= dv; acc0.z *= dv; acc0.w *= dv;
    acc1.x *= dv; acc1.y *= dv; acc1.z *= dv; acc1.w *= dv;
    acc2.x *= dv; acc2.y *= dv; acc2.z *= dv; acc2.w *= dv;
    acc3.x *= dv; acc3.y *= dv; acc3.z *= dv; acc3.w *= dv;

    // feature-major write: 16 rows, col gv; wave writes 256B contiguous per row
    int krow = c * 16;
    outAT[(size_t)(krow +  0) * NTOT + gv] = acc0.x;
    outAT[(size_t)(krow +  1) * NTOT + gv] = acc0.y;
    outAT[(size_t)(krow +  2) * NTOT + gv] = acc0.z;
    outAT[(size_t)(krow +  3) * NTOT + gv] = acc0.w;
    outAT[(size_t)(krow +  4) * NTOT + gv] = acc1.x;
    outAT[(size_t)(krow +  5) * NTOT + gv] = acc1.y;
    outAT[(size_t)(krow +  6) * NTOT + gv] = acc1.z;
    outAT[(size_t)(krow +  7) * NTOT + gv] = acc1.w;
    outAT[(size_t)(krow +  8) * NTOT + gv] = acc2.x;
    outAT[(size_t)(krow +  9) * NTOT + gv] = acc2.y;
    outAT[(size_t)(krow + 10) * NTOT + gv] = acc2.z;
    outAT[(size_t)(krow + 11) * NTOT + gv] = acc2.w;
    outAT[(size_t)(krow + 12) * NTOT + gv] = acc3.x;
    outAT[(size_t)(krow + 13) * NTOT + gv] = acc3.y;
    outAT[(size_t)(krow + 14) * NTOT + gv] = acc3.z;
    outAT[(size_t)(krow + 15) * NTOT + gv] = acc3.w;

    if (fvec && c == 0) {   // f_v = dinv_v*(dinv_v + sum dinv_s)
        __syncthreads();
        float* sdv = (float*)sy4;
        sdv[t] = dv;
        __syncthreads();
        float acc = dv;
        for (int j = 0; j < n; ++j) acc += sdv[ip[(size_t)j * NTOT]];
        fvec[gv] = dv * acc;
    }
}

// ---------------- fp32 GEMM 64x128 tile, 8x4 micro-tile, fused epilogue -----------
__global__ __launch_bounds__(256, 4) void gemm_k(const float* __restrict__ AT,
                                                 const float* __restrict__ W,
                                                 const float* __restrict__ bias,
                                                 float* __restrict__ outZ,
                                                 int K,
                                                 const float* __restrict__ fvec,
                                                 const float* __restrict__ gproj,
                                                 float* __restrict__ part,
                                                 const float* __restrict__ W3,
                                                 const int* __restrict__ cnt,
                                                 float* __restrict__ zout) {
    __shared__ float At[32][68];    // [k][row]
    __shared__ float Wt[32][132];   // [k][col]
    int t = threadIdx.x;
    int row0 = blockIdx.x * 64;
    int tx = t & 31;                // col group: cols tx*4..+3
    int ty = t >> 5;                // row group: rows ty*8..+7

    float acc[8][4];
#pragma unroll
    for (int i = 0; i < 8; ++i)
#pragma unroll
        for (int j = 0; j < 4; ++j) acc[i][j] = 0.f;

    for (int kt = 0; kt < K; kt += 32) {
        {   // stage A: straight b128 copy from feature-major AT
            int r4 = (t & 15) * 4, k2 = t >> 4;   // k2: 0..15
#pragma unroll
            for (int p = 0; p < 2; ++p) {
                int k = k2 + p * 16;
                float4 v4 = *(const float4*)&AT[(size_t)(kt + k) * NTOT + row0 + r4];
                *(float4*)&At[k][r4] = v4;
            }
        }
        {   // stage W: 32 k x 128 cols
            int c4 = (t & 31) * 4, kr = t >> 5;
#pragma unroll
            for (int p = 0; p < 4; ++p) {
                int k = kr + p * 8;
                *(float4*)&Wt[k][c4] = *(const float4*)&W[(size_t)(kt + k) * 128 + c4];
            }
        }
        __syncthreads();
#pragma unroll
        for (int k = 0; k < 32; ++k) {
            float4 a0 = *(const float4*)&At[k][ty * 8];
            float4 a1 = *(const float4*)&At[k][ty * 8 + 4];
            float4 w  = *(const float4*)&Wt[k][tx * 4];
            float a[8] = {a0.x, a0.y, a0.z, a0.w, a1.x, a1.y, a1.z, a1.w};
#pragma unroll
            for (int i = 0; i < 8; ++i) {
                acc[i][0] += a[i] * w.x;
                acc[i][1] += a[i] * w.y;
                acc[i][2] += a[i] * w.z;
                acc[i][3] += a[i] * w.w;
            }
        }
        __syncthreads();
    }

    int g = row0 >> 10;
    float b[4];
#pragma unroll
    for (int j = 0; j < 4; ++j) b[j] = bias[tx * 4 + j];
    float gp[4], fr[8];
    if (fvec) {
#pragma unroll
        for (int j = 0; j < 4; ++j) gp[j] = gproj[(size_t)g * 128 + tx * 4 + j];
#pragma unroll
        for (int i = 0; i < 8; ++i) fr[i] = fvec[row0 + ty * 8 + i];
    }
    float w3[4];
    if (zout) {
#pragma unroll
        for (int j = 0; j < 4; ++j) w3[j] = W3[tx * 4 + j];
    }
    float dvs[8];
#pragma unroll
    for (int i = 0; i < 8; ++i) dvs[i] = rsqrtf((float)cnt[row0 + ty * 8 + i] + 1.0f);
    float m[4];
#pragma unroll
    for (int j = 0; j < 4; ++j) m[j] = 0.f;   // relu floor
    float zp[8];

    int cc = tx >> 2, off = (tx & 3) * 4;
#pragma unroll
    for (int i = 0; i < 8; ++i) {
        int r = row0 + ty * 8 + i;
        float o[4];
        float zpi = 0.f;
#pragma unroll
        for (int j = 0; j < 4; ++j) {
            float v = acc[i][j] + b[j];
            if (fvec) v += fr[i] * gp[j];
            v = fmaxf(v, 0.f);
            if (part) m[j] = fmaxf(m[j], v);
            if (zout) zpi += v * w3[j];
            o[j] = v * dvs[i];              // fold dinv into output
        }
        zp[i] = zpi;
        if (outZ)
            *(float4*)&outZ[((size_t)cc * NTOT + r) * 16 + off] =
                make_float4(o[0], o[1], o[2], o[3]);
    }

    if (zout) {   // reduce partial dots across 32 col-groups -> z[row]
        float* zsm = &At[0][0];   // 64 rows x 32 = 2048 floats
        __syncthreads();
#pragma unroll
        for (int i = 0; i < 8; ++i) zsm[(ty * 8 + i) * 32 + tx] = zp[i];
        __syncthreads();
        if (t < 64) {
            float s = 0.f;
#pragma unroll
            for (int xg = 0; xg < 32; ++xg) s += zsm[t * 32 + xg];
            zout[row0 + t] = s * rsqrtf((float)cnt[row0 + t] + 1.0f);
        }
    }

    if (part) {   // per-graph col-max: reduce across 8 row-groups, then atomicMax
        float* sm = &At[0][0];    // 8 x 128 floats
        __syncthreads();
#pragma unroll
        for (int j = 0; j < 4; ++j) sm[ty * 128 + tx * 4 + j] = m[j];
        __syncthreads();
        for (int s = 4; s >= 1; s >>= 1) {
            if (ty < s) {
#pragma unroll
                for (int j = 0; j < 4; ++j) {
                    int idx = ty * 128 + tx * 4 + j;
                    sm[idx] = fmaxf(sm[idx], sm[(ty + s) * 128 + tx * 4 + j]);
                }
            }
            __syncthreads();
        }
        if (ty == 0) {
            int* pp = (int*)&part[(size_t)g * 128 + tx * 4];
#pragma unroll
            for (int j = 0; j < 4; ++j) atomicMax(pp + j, __float_as_int(sm[tx * 4 + j]));
        }
    }
}

// ---------------- glob = maxpool@Wf + bf ; gproj = glob @ W2[128:256,:] --------------
__global__ __launch_bounds__(128) void glob_k(const float* __restrict__ part,
                                              const float* __restrict__ Wf,
                                              const float* __restrict__ bf,
                                              const float* __restrict__ W2,
                                              float* __restrict__ gproj) {
    __shared__ float mp[128];
    __shared__ float gl[128];
    int g = blockIdx.x, t = threadIdx.x;
    mp[t] = part[(size_t)g * 128 + t];
    __syncthreads();
    float acc = bf[t];
    for (int k = 0; k < 128; ++k) acc += mp[k] * Wf[(size_t)k * 128 + t];
    gl[t] = acc;
    __syncthreads();
    float acc2 = 0.f;
    for (int k = 0; k < 128; ++k) acc2 += gl[k] * W2[(size_t)(128 + k) * 128 + t];
    gproj[(size_t)g * 128 + t] = acc2;
}

// ---------------- fused scalar-agg + top-K mask (one block per graph) ----------------
__global__ __launch_bounds__(256) void smask_k(const float* __restrict__ z,
                                               const unsigned short* __restrict__ col16,
                                               const int* __restrict__ cnt,
                                               const float* __restrict__ b3,
                                               float* __restrict__ out) {
    __shared__ float sz[1024];
    __shared__ float sl[1024];
    __shared__ float slo[1024];
    __shared__ float rv[256];
    __shared__ int   ri[256];
    __shared__ float sth;
    int g = blockIdx.x, t = threadIdx.x;
    int base = g << 10;
#pragma unroll
    for (int i = 0; i < 4; ++i) sz[t + 256 * i] = z[base + t + 256 * i];
    __syncthreads();
    float bb = b3[0];
#pragma unroll 1
    for (int i = 0; i < 4; ++i) {
        int v = t + 256 * i;
        int gv = base + v;
        int n = cnt[gv];
        float dv = rsqrtf((float)n + 1.0f);
        float acc = sz[v];
        const unsigned short* ip = col16 + gv;
        int j = 0;
        for (; j + 2 <= n; j += 2)
            acc += sz[ip[(size_t)j * NTOT]] + sz[ip[(size_t)(j + 1) * NTOT]];
        for (; j < n; ++j) acc += sz[ip[(size_t)j * NTOT]];
        float lg = acc * dv + bb;
        sl[v] = lg; slo[v] = lg;
    }
    __syncthreads();
    for (int pass = 0; pass < KSEL; ++pass) {
        float bv = -INFINITY;
        int bi = 0;
#pragma unroll
        for (int i = 0; i < 4; ++i) {
            float v = sl[t + 256 * i];
            if (v > bv) { bv = v; bi = t + 256 * i; }
        }
        rv[t] = bv; ri[t] = bi;
        __syncthreads();
        for (int s = 128; s > 0; s >>= 1) {
            if (t < s) {
                if (rv[t + s] > rv[t]) { rv[t] = rv[t + s]; ri[t] = ri[t + s]; }
            }
            __syncthreads();
        }
        if (t == 0) { sth = rv[0]; sl[ri[0]] = -INFINITY; }
        __syncthreads();
    }
    float th = sth;
#pragma unroll
    for (int i = 0; i < 4; ++i) {
        int v = t + 256 * i;
        out[base + v] = (slo[v] >= th) ? 1.f : 0.f;
    }
}

// =====================================================================================
extern "C" void kernel_launch(void* const* d_in, const int* in_sizes, int n_in,
                              void* d_out, int out_size, void* d_ws, size_t ws_size,
                              hipStream_t stream) {
    const float* x        = (const float*)d_in[0];
    const int*   edge_src = (const int*)d_in[1];
    const int*   edge_dst = (const int*)d_in[2];
    const float* W0 = (const float*)d_in[4];
    const float* b0 = (const float*)d_in[5];
    const float* W1 = (const float*)d_in[6];
    const float* b1 = (const float*)d_in[7];
    const float* Wf = (const float*)d_in[8];
    const float* bf = (const float*)d_in[9];
    const float* W2 = (const float*)d_in[10];
    const float* b2 = (const float*)d_in[11];
    const float* W3 = (const float*)d_in[12];
    const float* b3 = (const float*)d_in[13];
    float* out = (float*)d_out;

    char* w = (char*)d_ws;
    int*            cnt    = (int*)w;            w += (size_t)NTOT * 4;
    unsigned short* col16  = (unsigned short*)w; w += (size_t)NTOT * MAXDEG * 2;
    float*          fvec   = (float*)w;          w += (size_t)NTOT * 4;
    float*          P      = (float*)w;          w += (size_t)NTOT * 128 * 4;  // AT
    float*          Q      = (float*)w;          w += (size_t)NTOT * 128 * 4;  // Z
    float*          part   = (float*)w;          w += (size_t)NB * 128 * 4;
    float*          gproj  = (float*)w;          w += (size_t)NB * 128 * 4;
    float*          z      = (float*)w;          w += (size_t)NTOT * 4;

    init_k<<<NTOT / 256, 256, 0, stream>>>(cnt, part);
    csr_k<<<ETOT / 256, 256, 0, stream>>>(edge_src, edge_dst, cnt, col16);

    // conv0: AT0 = agg(x) [64 rows]; Z0 = relu(AT0@W0+b0)*dinv, fused maxpool -> part
    agg_k<<<NB * 4, 1024, 0, stream>>>(nullptr, x, col16, cnt, P, 2, nullptr);
    gemm_k<<<NTOT / 64, 256, 0, stream>>>(P, W0, b0, Q, FEAT, nullptr, nullptr, part,
                                          nullptr, cnt, nullptr);

    glob_k<<<NB, 128, 0, stream>>>(part, Wf, bf, W2, gproj);

    // conv1 twice (same weights)
    agg_k<<<NB * 8, 1024, 0, stream>>>(Q, nullptr, col16, cnt, P, 3, nullptr);
    gemm_k<<<NTOT / 64, 256, 0, stream>>>(P, W1, b1, Q, HID, nullptr, nullptr, nullptr,
                                          nullptr, cnt, nullptr);
    agg_k<<<NB * 8, 1024, 0, stream>>>(Q, nullptr, col16, cnt, P, 3, nullptr);
    gemm_k<<<NTOT / 64, 256, 0, stream>>>(P, W1, b1, Q, HID, nullptr, nullptr, nullptr,
                                          nullptr, cnt, nullptr);

    // conv2: AT = agg(Z2) (+fvec); z = dinv*(relu(AT@W2a + f*gproj + b2)@W3)
    agg_k<<<NB * 8, 1024, 0, stream>>>(Q, nullptr, col16, cnt, P, 3, fvec);
    gemm_k<<<NTOT / 64, 256, 0, stream>>>(P, W2, b2, nullptr, HID, fvec, gproj, nullptr,
                                          W3, cnt, z);

    // logits = agg_scalar(z) + b3, then per-graph top-10 mask (fused)
    smask_k<<<NB, 256, 0, stream>>>(z, col16, cnt, b3, out);
}

// Round 10
// 360.985 us; speedup vs baseline: 1.0910x; 1.0910x over previous
//
#include <hip/hip_runtime.h>
#include <math.h>

#define NB    64        // graphs
#define NPER  1024      // nodes per graph
#define NTOT  65536     // total nodes
#define ETOT  1048576   // edges
#define FEAT  64
#define HID   128
#define KSEL  10
#define MAXDEG 64       // CSR slot capacity per node (max in-degree ~40)

// Pipeline (agg commuted before the weight multiply, dinv folded into gemm output):
//   AT = agg(Z)            agg_k  : LDS-staged gather, 4 lanes/node; out feature-major
//   Z' = relu(AT@W+b)*dinv gemm_k : 64x128 tile; A-stage = straight b128 copy
// Index layout: PAIR-PACKED slot-major colp[p][v] = (slot2p+1 <<16)|slot2p, u32.
// Feature layouts: Z chunk-major C[c][v][16]; AT feature-major [k][v].

// ---------------- init: zero cnt + part (replaces two memsets) ----------------------
__global__ __launch_bounds__(256) void init_k(int* __restrict__ cnt,
                                              float* __restrict__ part) {
    int v = blockIdx.x * 256 + threadIdx.x;
    cnt[v] = 0;
    if (v < NB * 128) part[v] = 0.f;
}

// ---------------- CSR build (pair-packed slot-major, u16 halves) --------------------
__global__ __launch_bounds__(256) void csr_k(const int* __restrict__ src,
                                             const int* __restrict__ dst,
                                             int* __restrict__ cnt,
                                             unsigned short* __restrict__ col16) {
    int e = blockIdx.x * 256 + threadIdx.x;
    if (e >= ETOT) return;
    int d = dst[e];
    int s = src[e];
    int pos = atomicAdd(&cnt[d], 1);
    // u16 element index inside the pair-packed u32 array colp[p][v]
    col16[((size_t)(pos >> 1) * NTOT + d) * 2 + (pos & 1)] =
        (unsigned short)(s & (NPER - 1));
}

// ---------------- LDS-staged aggregation, 4 lanes per node -------------------------
// block=(graph g, chunk c); 1024 threads; lane quad owns one node's float4 slot f4.
// Z input pre-scaled by dinv (gemm epilogue); x (conv0) scaled at staging.
__global__ __launch_bounds__(1024) void agg_k(const float* __restrict__ Z,
                                              const float* __restrict__ x,
                                              const unsigned int* __restrict__ colp,
                                              const int* __restrict__ cnt,
                                              float* __restrict__ outAT,
                                              int cshift,
                                              float* __restrict__ fvec) {
    __shared__ float4 sy4[4096];   // 64 KB
    int t = threadIdx.x;
    int g = blockIdx.x >> cshift;
    int c = blockIdx.x & ((1 << cshift) - 1);
    int gbase = g << 10;

    if (x) {
#pragma unroll
        for (int j = 0; j < 4; ++j) {
            int fl = j * 1024 + t;
            int v = fl >> 2, q = fl & 3;
            float dvv = rsqrtf((float)cnt[gbase + v] + 1.0f);
            float4 z = *(const float4*)&x[(size_t)(gbase + v) * FEAT + c * 16 + q * 4];
            z.x *= dvv; z.y *= dvv; z.z *= dvv; z.w *= dvv;
            sy4[fl] = z;
        }
    } else {
        const float4* Zg4 = (const float4*)(Z + ((size_t)c * NTOT + gbase) * 16);
#pragma unroll
        for (int j = 0; j < 4; ++j) sy4[j * 1024 + t] = Zg4[j * 1024 + t];
    }
    __syncthreads();

    int f4 = t & 3;
    int vl = t >> 2;                        // 0..255

#pragma unroll 1
    for (int pass = 0; pass < 4; ++pass) {
        int v = pass * 256 + vl;
        int gv = gbase + v;
        int n = cnt[gv];
        float dv = rsqrtf((float)n + 1.0f);
        const unsigned int* ip = colp + gv;     // stride NTOT per pair
        float4 acc = sy4[v * 4 + f4];           // self term
        int np = n >> 1;
        for (int i = 0; i < np; ++i) {
            unsigned int pw = ip[(size_t)i * NTOT];
            int a = pw & 0xFFFF, b = pw >> 16;
            float4 ya = sy4[a * 4 + f4];
            float4 yb = sy4[b * 4 + f4];
            acc.x += ya.x + yb.x;
            acc.y += ya.y + yb.y;
            acc.z += ya.z + yb.z;
            acc.w += ya.w + yb.w;
        }
        if (n & 1) {
            unsigned int pw = ip[(size_t)np * NTOT];
            float4 ya = sy4[(int)(pw & 0xFFFF) * 4 + f4];
            acc.x += ya.x; acc.y += ya.y; acc.z += ya.z; acc.w += ya.w;
        }
        acc.x *= dv; acc.y *= dv; acc.z *= dv; acc.w *= dv;
        int krow = c * 16 + f4 * 4;             // feature-major write: 4 rows, col gv
        outAT[(size_t)(krow + 0) * NTOT + gv] = acc.x;
        outAT[(size_t)(krow + 1) * NTOT + gv] = acc.y;
        outAT[(size_t)(krow + 2) * NTOT + gv] = acc.z;
        outAT[(size_t)(krow + 3) * NTOT + gv] = acc.w;
    }

    if (fvec && c == 0) {   // f_v = dinv_v*(dinv_v + sum dinv_s)
        __syncthreads();
        float* sdv = (float*)sy4;
        float dv = rsqrtf((float)cnt[gbase + t] + 1.0f);
        sdv[t] = dv;
        __syncthreads();
        int n = cnt[gbase + t];
        float acc = dv;
        const unsigned int* ip = colp + gbase + t;
        int np = n >> 1;
        for (int i = 0; i < np; ++i) {
            unsigned int pw = ip[(size_t)i * NTOT];
            acc += sdv[pw & 0xFFFF] + sdv[pw >> 16];
        }
        if (n & 1) acc += sdv[ip[(size_t)np * NTOT] & 0xFFFF];
        fvec[gbase + t] = dv * acc;
    }
}

// ---------------- fp32 GEMM 64x128 tile, 8x4 micro-tile, fused epilogue -----------
__global__ __launch_bounds__(256, 4) void gemm_k(const float* __restrict__ AT,
                                                 const float* __restrict__ W,
                                                 const float* __restrict__ bias,
                                                 float* __restrict__ outZ,
                                                 int K,
                                                 const float* __restrict__ fvec,
                                                 const float* __restrict__ gproj,
                                                 float* __restrict__ part,
                                                 const float* __restrict__ W3,
                                                 const int* __restrict__ cnt,
                                                 float* __restrict__ zout) {
    __shared__ float At[32][68];    // [k][row]
    __shared__ float Wt[32][132];   // [k][col]
    int t = threadIdx.x;
    int row0 = blockIdx.x * 64;
    int tx = t & 31;                // col group: cols tx*4..+3
    int ty = t >> 5;                // row group: rows ty*8..+7

    float acc[8][4];
#pragma unroll
    for (int i = 0; i < 8; ++i)
#pragma unroll
        for (int j = 0; j < 4; ++j) acc[i][j] = 0.f;

    for (int kt = 0; kt < K; kt += 32) {
        {   // stage A: straight b128 copy from feature-major AT
            int r4 = (t & 15) * 4, k2 = t >> 4;   // k2: 0..15
#pragma unroll
            for (int p = 0; p < 2; ++p) {
                int k = k2 + p * 16;
                float4 v4 = *(const float4*)&AT[(size_t)(kt + k) * NTOT + row0 + r4];
                *(float4*)&At[k][r4] = v4;
            }
        }
        {   // stage W: 32 k x 128 cols
            int c4 = (t & 31) * 4, kr = t >> 5;
#pragma unroll
            for (int p = 0; p < 4; ++p) {
                int k = kr + p * 8;
                *(float4*)&Wt[k][c4] = *(const float4*)&W[(size_t)(kt + k) * 128 + c4];
            }
        }
        __syncthreads();
#pragma unroll
        for (int k = 0; k < 32; ++k) {
            float4 a0 = *(const float4*)&At[k][ty * 8];
            float4 a1 = *(const float4*)&At[k][ty * 8 + 4];
            float4 w  = *(const float4*)&Wt[k][tx * 4];
            float a[8] = {a0.x, a0.y, a0.z, a0.w, a1.x, a1.y, a1.z, a1.w};
#pragma unroll
            for (int i = 0; i < 8; ++i) {
                acc[i][0] += a[i] * w.x;
                acc[i][1] += a[i] * w.y;
                acc[i][2] += a[i] * w.z;
                acc[i][3] += a[i] * w.w;
            }
        }
        __syncthreads();
    }

    int g = row0 >> 10;
    float b[4];
#pragma unroll
    for (int j = 0; j < 4; ++j) b[j] = bias[tx * 4 + j];
    float gp[4], fr[8];
    if (fvec) {
#pragma unroll
        for (int j = 0; j < 4; ++j) gp[j] = gproj[(size_t)g * 128 + tx * 4 + j];
#pragma unroll
        for (int i = 0; i < 8; ++i) fr[i] = fvec[row0 + ty * 8 + i];
    }
    float w3[4];
    if (zout) {
#pragma unroll
        for (int j = 0; j < 4; ++j) w3[j] = W3[tx * 4 + j];
    }
    float dvs[8];
#pragma unroll
    for (int i = 0; i < 8; ++i) dvs[i] = rsqrtf((float)cnt[row0 + ty * 8 + i] + 1.0f);
    float m[4];
#pragma unroll
    for (int j = 0; j < 4; ++j) m[j] = 0.f;   // relu floor
    float zp[8];

    int cc = tx >> 2, off = (tx & 3) * 4;
#pragma unroll
    for (int i = 0; i < 8; ++i) {
        int r = row0 + ty * 8 + i;
        float o[4];
        float zpi = 0.f;
#pragma unroll
        for (int j = 0; j < 4; ++j) {
            float v = acc[i][j] + b[j];
            if (fvec) v += fr[i] * gp[j];
            v = fmaxf(v, 0.f);
            if (part) m[j] = fmaxf(m[j], v);
            if (zout) zpi += v * w3[j];
            o[j] = v * dvs[i];              // fold dinv into output
        }
        zp[i] = zpi;
        if (outZ)
            *(float4*)&outZ[((size_t)cc * NTOT + r) * 16 + off] =
                make_float4(o[0], o[1], o[2], o[3]);
    }

    if (zout) {   // reduce partial dots across 32 col-groups -> z[row]
        float* zsm = &At[0][0];   // 64 rows x 32 = 2048 floats
        __syncthreads();
#pragma unroll
        for (int i = 0; i < 8; ++i) zsm[(ty * 8 + i) * 32 + tx] = zp[i];
        __syncthreads();
        if (t < 64) {
            float s = 0.f;
#pragma unroll
            for (int xg = 0; xg < 32; ++xg) s += zsm[t * 32 + xg];
            zout[row0 + t] = s * rsqrtf((float)cnt[row0 + t] + 1.0f);
        }
    }

    if (part) {   // per-graph col-max: reduce across 8 row-groups, then atomicMax
        float* sm = &At[0][0];    // 8 x 128 floats
        __syncthreads();
#pragma unroll
        for (int j = 0; j < 4; ++j) sm[ty * 128 + tx * 4 + j] = m[j];
        __syncthreads();
        for (int s = 4; s >= 1; s >>= 1) {
            if (ty < s) {
#pragma unroll
                for (int j = 0; j < 4; ++j) {
                    int idx = ty * 128 + tx * 4 + j;
                    sm[idx] = fmaxf(sm[idx], sm[(ty + s) * 128 + tx * 4 + j]);
                }
            }
            __syncthreads();
        }
        if (ty == 0) {
            int* pp = (int*)&part[(size_t)g * 128 + tx * 4];
#pragma unroll
            for (int j = 0; j < 4; ++j) atomicMax(pp + j, __float_as_int(sm[tx * 4 + j]));
        }
    }
}

// ---------------- glob = maxpool@Wf + bf ; gproj = glob @ W2[128:256,:] --------------
__global__ __launch_bounds__(128) void glob_k(const float* __restrict__ part,
                                              const float* __restrict__ Wf,
                                              const float* __restrict__ bf,
                                              const float* __restrict__ W2,
                                              float* __restrict__ gproj) {
    __shared__ float mp[128];
    __shared__ float gl[128];
    int g = blockIdx.x, t = threadIdx.x;
    mp[t] = part[(size_t)g * 128 + t];
    __syncthreads();
    float acc = bf[t];
    for (int k = 0; k < 128; ++k) acc += mp[k] * Wf[(size_t)k * 128 + t];
    gl[t] = acc;
    __syncthreads();
    float acc2 = 0.f;
    for (int k = 0; k < 128; ++k) acc2 += gl[k] * W2[(size_t)(128 + k) * 128 + t];
    gproj[(size_t)g * 128 + t] = acc2;
}

// ---------------- fused scalar-agg + top-K mask (one block per graph) ----------------
__global__ __launch_bounds__(256) void smask_k(const float* __restrict__ z,
                                               const unsigned int* __restrict__ colp,
                                               const int* __restrict__ cnt,
                                               const float* __restrict__ b3,
                                               float* __restrict__ out) {
    __shared__ float sz[1024];
    __shared__ float sl[1024];
    __shared__ float slo[1024];
    __shared__ float rv[256];
    __shared__ int   ri[256];
    __shared__ float sth;
    int g = blockIdx.x, t = threadIdx.x;
    int base = g << 10;
#pragma unroll
    for (int i = 0; i < 4; ++i) sz[t + 256 * i] = z[base + t + 256 * i];
    __syncthreads();
    float bb = b3[0];
#pragma unroll 1
    for (int i = 0; i < 4; ++i) {
        int v = t + 256 * i;
        int gv = base + v;
        int n = cnt[gv];
        float dv = rsqrtf((float)n + 1.0f);
        float acc = sz[v];
        const unsigned int* ip = colp + gv;
        int np = n >> 1;
        for (int j = 0; j < np; ++j) {
            unsigned int pw = ip[(size_t)j * NTOT];
            acc += sz[pw & 0xFFFF] + sz[pw >> 16];
        }
        if (n & 1) acc += sz[ip[(size_t)np * NTOT] & 0xFFFF];
        float lg = acc * dv + bb;
        sl[v] = lg; slo[v] = lg;
    }
    __syncthreads();
    for (int pass = 0; pass < KSEL; ++pass) {
        float bv = -INFINITY;
        int bi = 0;
#pragma unroll
        for (int i = 0; i < 4; ++i) {
            float v = sl[t + 256 * i];
            if (v > bv) { bv = v; bi = t + 256 * i; }
        }
        rv[t] = bv; ri[t] = bi;
        __syncthreads();
        for (int s = 128; s > 0; s >>= 1) {
            if (t < s) {
                if (rv[t + s] > rv[t]) { rv[t] = rv[t + s]; ri[t] = ri[t + s]; }
            }
            __syncthreads();
        }
        if (t == 0) { sth = rv[0]; sl[ri[0]] = -INFINITY; }
        __syncthreads();
    }
    float th = sth;
#pragma unroll
    for (int i = 0; i < 4; ++i) {
        int v = t + 256 * i;
        out[base + v] = (slo[v] >= th) ? 1.f : 0.f;
    }
}

// =====================================================================================
extern "C" void kernel_launch(void* const* d_in, const int* in_sizes, int n_in,
                              void* d_out, int out_size, void* d_ws, size_t ws_size,
                              hipStream_t stream) {
    const float* x        = (const float*)d_in[0];
    const int*   edge_src = (const int*)d_in[1];
    const int*   edge_dst = (const int*)d_in[2];
    const float* W0 = (const float*)d_in[4];
    const float* b0 = (const float*)d_in[5];
    const float* W1 = (const float*)d_in[6];
    const float* b1 = (const float*)d_in[7];
    const float* Wf = (const float*)d_in[8];
    const float* bf = (const float*)d_in[9];
    const float* W2 = (const float*)d_in[10];
    const float* b2 = (const float*)d_in[11];
    const float* W3 = (const float*)d_in[12];
    const float* b3 = (const float*)d_in[13];
    float* out = (float*)d_out;

    char* w = (char*)d_ws;
    int*            cnt    = (int*)w;            w += (size_t)NTOT * 4;
    unsigned short* col16  = (unsigned short*)w; w += (size_t)NTOT * MAXDEG * 2;
    float*          fvec   = (float*)w;          w += (size_t)NTOT * 4;
    float*          P      = (float*)w;          w += (size_t)NTOT * 128 * 4;  // AT
    float*          Q      = (float*)w;          w += (size_t)NTOT * 128 * 4;  // Z
    float*          part   = (float*)w;          w += (size_t)NB * 128 * 4;
    float*          gproj  = (float*)w;          w += (size_t)NB * 128 * 4;
    float*          z      = (float*)w;          w += (size_t)NTOT * 4;
    const unsigned int* colp = (const unsigned int*)col16;

    init_k<<<NTOT / 256, 256, 0, stream>>>(cnt, part);
    csr_k<<<ETOT / 256, 256, 0, stream>>>(edge_src, edge_dst, cnt, col16);

    // conv0: AT0 = agg(x) [64 rows]; Z0 = relu(AT0@W0+b0)*dinv, fused maxpool -> part
    agg_k<<<NB * 4, 1024, 0, stream>>>(nullptr, x, colp, cnt, P, 2, nullptr);
    gemm_k<<<NTOT / 64, 256, 0, stream>>>(P, W0, b0, Q, FEAT, nullptr, nullptr, part,
                                          nullptr, cnt, nullptr);

    glob_k<<<NB, 128, 0, stream>>>(part, Wf, bf, W2, gproj);

    // conv1 twice (same weights)
    agg_k<<<NB * 8, 1024, 0, stream>>>(Q, nullptr, colp, cnt, P, 3, nullptr);
    gemm_k<<<NTOT / 64, 256, 0, stream>>>(P, W1, b1, Q, HID, nullptr, nullptr, nullptr,
                                          nullptr, cnt, nullptr);
    agg_k<<<NB * 8, 1024, 0, stream>>>(Q, nullptr, colp, cnt, P, 3, nullptr);
    gemm_k<<<NTOT / 64, 256, 0, stream>>>(P, W1, b1, Q, HID, nullptr, nullptr, nullptr,
                                          nullptr, cnt, nullptr);

    // conv2: AT = agg(Z2) (+fvec); z = dinv*(relu(AT@W2a + f*gproj + b2)@W3)
    agg_k<<<NB * 8, 1024, 0, stream>>>(Q, nullptr, colp, cnt, P, 3, fvec);
    gemm_k<<<NTOT / 64, 256, 0, stream>>>(P, W2, b2, nullptr, HID, fvec, gproj, nullptr,
                                          W3, cnt, z);

    // logits = agg_scalar(z) + b3, then per-graph top-10 mask (fused)
    smask_k<<<NB, 256, 0, stream>>>(z, colp, cnt, b3, out);
}